// Round 3
// baseline (7745.357 us; speedup 1.0000x reference)
//
#include <hip/hip_runtime.h>
#include <math.h>
#include <stdint.h>

#define N_EMBED   2048
#define N_EXPERTS 64
#define TOP_K     8
#define TM        32            // tokens per block
#define TW        8             // tokens per wave
#define KC        32            // K-chunk
#define NC        (N_EMBED / KC)

// monotone map fp64 -> u64 (bigger value => bigger key), low 6 bits = tie-break
// by lane (lower expert index wins ties, matching lax.top_k)
__device__ __forceinline__ uint64_t mono_key(double v, int lane) {
    uint64_t u = (uint64_t)__double_as_longlong(v);
    u = (u >> 63) ? ~u : (u | 0x8000000000000000ULL);
    return (u & ~63ULL) | (uint64_t)(63 - lane);
}
__device__ __forceinline__ double key_val(uint64_t k) {
    uint64_t u = k & ~63ULL;
    u = (u >> 63) ? (u & 0x7FFFFFFFFFFFFFFFULL) : ~u;
    return __longlong_as_double((long long)u);
}

__global__ __launch_bounds__(256, 3)
void noisy_topk_kernel(const float* __restrict__ x,
                       const float* __restrict__ Wl, const float* __restrict__ bl,
                       const float* __restrict__ Wn, const float* __restrict__ bn,
                       float* __restrict__ out, int n_tokens) {
    __shared__ double Wt[2][KC][N_EXPERTS + 1];  // 33,280 B, transposed, padded
    __shared__ double xs[2][TM][KC];             // 16,384 B, fp64 x chunks

    const int tid  = threadIdx.x;
    const int lane = tid & 63;                   // lane = expert
    const int wave = tid >> 6;
    const int t0   = blockIdx.x * TM;
    const int tb   = wave * TW;

    // staging ownership
    const int se  = tid >> 2;                    // expert row 0..63
    const int sk8 = (tid & 3) * 8;               // 8 k's of that row
    const int st  = tid >> 3;                    // token 0..31
    const int sk4 = (tid & 7) * 4;               // 4 k's of that token

    double acc[TW];
#pragma unroll
    for (int t = 0; t < TW; ++t) acc[t] = 0.0;

    const double myb = (double)bl[lane] + (double)bn[lane];

    float4 wl0, wl1, wn0, wn1, xv;
    auto issue = [&](int c) {
        const int kc = c * KC;
        const float* wlp = Wl + (size_t)se * N_EMBED + kc + sk8;
        const float* wnp = Wn + (size_t)se * N_EMBED + kc + sk8;
        wl0 = *reinterpret_cast<const float4*>(wlp);
        wl1 = *reinterpret_cast<const float4*>(wlp + 4);
        wn0 = *reinterpret_cast<const float4*>(wnp);
        wn1 = *reinterpret_cast<const float4*>(wnp + 4);
        xv  = *reinterpret_cast<const float4*>(x + (size_t)(t0 + st) * N_EMBED + kc + sk4);
    };
    auto commit = [&](int buf) {
        // combined weights, exact in fp64, transposed
        Wt[buf][sk8 + 0][se] = (double)wl0.x + (double)wn0.x;
        Wt[buf][sk8 + 1][se] = (double)wl0.y + (double)wn0.y;
        Wt[buf][sk8 + 2][se] = (double)wl0.z + (double)wn0.z;
        Wt[buf][sk8 + 3][se] = (double)wl0.w + (double)wn0.w;
        Wt[buf][sk8 + 4][se] = (double)wl1.x + (double)wn1.x;
        Wt[buf][sk8 + 5][se] = (double)wl1.y + (double)wn1.y;
        Wt[buf][sk8 + 6][se] = (double)wl1.z + (double)wn1.z;
        Wt[buf][sk8 + 7][se] = (double)wl1.w + (double)wn1.w;
        // x converted once at staging (amortized over 64 expert lanes)
        double2 a, b;
        a.x = (double)xv.x; a.y = (double)xv.y;
        b.x = (double)xv.z; b.y = (double)xv.w;
        *reinterpret_cast<double2*>(&xs[buf][st][sk4])     = a;
        *reinterpret_cast<double2*>(&xs[buf][st][sk4 + 2]) = b;
    };

    issue(0);
    commit(0);
    __syncthreads();

    int cur = 0;
    for (int c = 0; c < NC; ++c) {
        if (c + 1 < NC) issue(c + 1);           // early issue: hide global latency

        for (int kk = 0; kk < KC; kk += 4) {
            const double w0 = Wt[cur][kk + 0][lane];   // conflict-free b64
            const double w1 = Wt[cur][kk + 1][lane];
            const double w2 = Wt[cur][kk + 2][lane];
            const double w3 = Wt[cur][kk + 3][lane];
#pragma unroll
            for (int t = 0; t < TW; ++t) {
                const double2 xa = *reinterpret_cast<const double2*>(&xs[cur][tb + t][kk]);
                const double2 xb = *reinterpret_cast<const double2*>(&xs[cur][tb + t][kk + 2]);
                acc[t] = fma(xa.x, w0, acc[t]);
                acc[t] = fma(xa.y, w1, acc[t]);
                acc[t] = fma(xb.x, w2, acc[t]);
                acc[t] = fma(xb.y, w3, acc[t]);
            }
        }

        if (c + 1 < NC) commit(cur ^ 1);        // write-late into other buffer
        __syncthreads();
        cur ^= 1;
    }

    // ---- wave-parallel top-8 + softmax + stores (no LDS, no divergence) ----
    float* out_router = out;
    float* out_idx    = out + (size_t)n_tokens * N_EXPERTS;

#pragma unroll
    for (int t = 0; t < TW; ++t) {
        const double v = acc[t] + myb;
        uint64_t mykey = mono_key(v, lane);

        float pv[TOP_K]; int pi[TOP_K];
        double vtop0 = 0.0;
#pragma unroll
        for (int j = 0; j < TOP_K; ++j) {
            uint64_t k = mykey;
#pragma unroll
            for (int m = 32; m >= 1; m >>= 1) {
                uint64_t o = (uint64_t)__shfl_xor((unsigned long long)k, m);
                k = (o > k) ? o : k;
            }
            const int widx = 63 - (int)(k & 63);
            const double wv = key_val(k);
            if (j == 0) vtop0 = wv;
            pv[j] = __expf((float)(wv - vtop0));
            pi[j] = widx;
            if (lane == widx) mykey = 0;        // remove winner
        }
        float s = 0.f;
#pragma unroll
        for (int j = 0; j < TOP_K; ++j) s += pv[j];
        const float inv = 1.f / s;

        float r = 0.f;
#pragma unroll
        for (int j = 0; j < TOP_K; ++j) r = (lane == pi[j]) ? pv[j] * inv : r;
        out_router[(size_t)(t0 + tb + t) * N_EXPERTS + lane] = r;

        float iv = 0.f;
#pragma unroll
        for (int j = 0; j < TOP_K; ++j) iv = (lane == j) ? (float)pi[j] : iv;
        if (lane < TOP_K)
            out_idx[(size_t)(t0 + tb + t) * TOP_K + lane] = iv;
    }
}

extern "C" void kernel_launch(void* const* d_in, const int* in_sizes, int n_in,
                              void* d_out, int out_size, void* d_ws, size_t ws_size,
                              hipStream_t stream) {
    const float* x  = (const float*)d_in[0];
    const float* Wl = (const float*)d_in[1];
    const float* bl = (const float*)d_in[2];
    const float* Wn = (const float*)d_in[3];
    const float* bn = (const float*)d_in[4];
    float* out = (float*)d_out;

    int n_tokens = in_sizes[0] / N_EMBED;          // 16384
    int grid = (n_tokens + TM - 1) / TM;           // 512

    hipLaunchKernelGGL(noisy_topk_kernel, dim3(grid), dim3(256), 0, stream,
                       x, Wl, bl, Wn, bn, out, n_tokens);
}

// Round 4
// 278.170 us; speedup vs baseline: 27.8440x; 27.8440x over previous
//
#include <hip/hip_runtime.h>
#include <math.h>
#include <stdint.h>

#define N_EMBED   2048
#define N_EXPERTS 64
#define TOP_K     8
#define TM        32            // tokens per block
#define TW        8             // tokens per wave
#define KC        64            // K-chunk
#define NC        (N_EMBED / KC)

// monotone map fp64 -> u64 (bigger value => bigger key), low 6 bits = tie-break
// by lane so lower expert index wins ties (matches lax.top_k)
__device__ __forceinline__ uint64_t mono_key(double v, int lane) {
    uint64_t u = (uint64_t)__double_as_longlong(v);
    u = (u >> 63) ? ~u : (u | 0x8000000000000000ULL);
    return (u & ~63ULL) | (uint64_t)(63 - lane);
}
__device__ __forceinline__ double key_val(uint64_t k) {
    uint64_t u = k & ~63ULL;
    u = (u >> 63) ? (u & 0x7FFFFFFFFFFFFFFFULL) : ~u;
    return __longlong_as_double((long long)u);
}

__global__ __launch_bounds__(256, 2)
void noisy_topk_kernel(const float* __restrict__ x,
                       const float* __restrict__ Wl, const float* __restrict__ bl,
                       const float* __restrict__ Wn, const float* __restrict__ bn,
                       float* __restrict__ out, int n_tokens) {
    __shared__ double Wt[KC][N_EXPERTS];   // 32 KB, transposed: Wt[k][e]
    __shared__ double xs[TM][KC];          // 16 KB, fp64 x chunk

    const int tid  = threadIdx.x;
    const int lane = tid & 63;             // lane = expert
    const int wave = tid >> 6;
    const int t0   = blockIdx.x * TM;
    const int tb   = wave * TW;

    // fixed staging ownership
    const int se = tid >> 2;               // W: expert row 0..63
    const int sk = (tid & 3) * 16;         // W: 16 consecutive k
    const int st = tid >> 3;               // x: token 0..31
    const int sx = (tid & 7) * 8;          // x: 8 consecutive k

    double acc[TW];
#pragma unroll
    for (int t = 0; t < TW; ++t) acc[t] = 0.0;

    const double myb = (double)bl[lane] + (double)bn[lane];

    for (int c = 0; c < NC; ++c) {
        const int kc = c * KC;
        __syncthreads();                   // previous chunk's reads complete

        // ---- stage combined W chunk (fp64, transposed), coalesced reads ----
        const float* wlp = Wl + (size_t)se * N_EMBED + kc + sk;
        const float* wnp = Wn + (size_t)se * N_EMBED + kc + sk;
#pragma unroll
        for (int i = 0; i < 4; ++i) {
            const float4 a = *reinterpret_cast<const float4*>(wlp + 4 * i);
            const float4 b = *reinterpret_cast<const float4*>(wnp + 4 * i);
            Wt[sk + 4 * i + 0][se] = (double)a.x + (double)b.x;
            Wt[sk + 4 * i + 1][se] = (double)a.y + (double)b.y;
            Wt[sk + 4 * i + 2][se] = (double)a.z + (double)b.z;
            Wt[sk + 4 * i + 3][se] = (double)a.w + (double)b.w;
        }
        // ---- stage x chunk, converted to fp64 once here (not per-FMA) ----
        {
            const float* xp = x + (size_t)(t0 + st) * N_EMBED + kc + sx;
            const float4 a = *reinterpret_cast<const float4*>(xp);
            const float4 b = *reinterpret_cast<const float4*>(xp + 4);
            xs[st][sx + 0] = (double)a.x;
            xs[st][sx + 1] = (double)a.y;
            xs[st][sx + 2] = (double)a.z;
            xs[st][sx + 3] = (double)a.w;
            xs[st][sx + 4] = (double)b.x;
            xs[st][sx + 5] = (double)b.y;
            xs[st][sx + 6] = (double)b.z;
            xs[st][sx + 7] = (double)b.w;
        }
        __syncthreads();

        // ---- compute: lane = expert; w via conflict-free b64, x via broadcast ----
#pragma unroll 4
        for (int kk = 0; kk < KC; kk += 4) {
            const double w0 = Wt[kk + 0][lane];
            const double w1 = Wt[kk + 1][lane];
            const double w2 = Wt[kk + 2][lane];
            const double w3 = Wt[kk + 3][lane];
#pragma unroll
            for (int t = 0; t < TW; ++t) {
                const double2 p = *reinterpret_cast<const double2*>(&xs[tb + t][kk]);
                const double2 q = *reinterpret_cast<const double2*>(&xs[tb + t][kk + 2]);
                acc[t] = fma(p.x, w0, acc[t]);
                acc[t] = fma(p.y, w1, acc[t]);
                acc[t] = fma(q.x, w2, acc[t]);
                acc[t] = fma(q.y, w3, acc[t]);
            }
        }
    }

    // ---- wave-parallel top-8 + softmax + stores ----
    float* out_router = out;
    float* out_idx    = out + (size_t)n_tokens * N_EXPERTS;

#pragma unroll
    for (int t = 0; t < TW; ++t) {
        const double v = acc[t] + myb;
        uint64_t mykey = mono_key(v, lane);

        float pv[TOP_K]; int pi[TOP_K];
        double vtop0 = 0.0;
#pragma unroll
        for (int j = 0; j < TOP_K; ++j) {
            uint64_t k = mykey;
#pragma unroll
            for (int m = 32; m >= 1; m >>= 1) {
                uint64_t o = (uint64_t)__shfl_xor((unsigned long long)k, m);
                k = (o > k) ? o : k;
            }
            const int widx = 63 - (int)(k & 63);
            const double wv = key_val(k);
            if (j == 0) vtop0 = wv;
            pv[j] = __expf((float)(wv - vtop0));
            pi[j] = widx;
            if (lane == widx) mykey = 0;        // remove winner
        }
        float s = 0.f;
#pragma unroll
        for (int j = 0; j < TOP_K; ++j) s += pv[j];
        const float inv = 1.f / s;

        float r = 0.f;
#pragma unroll
        for (int j = 0; j < TOP_K; ++j) r = (lane == pi[j]) ? pv[j] * inv : r;
        out_router[(size_t)(t0 + tb + t) * N_EXPERTS + lane] = r;

        float iv = 0.f;
#pragma unroll
        for (int j = 0; j < TOP_K; ++j) iv = (lane == j) ? (float)pi[j] : iv;
        if (lane < TOP_K)
            out_idx[(size_t)(t0 + tb + t) * TOP_K + lane] = iv;
    }
}

extern "C" void kernel_launch(void* const* d_in, const int* in_sizes, int n_in,
                              void* d_out, int out_size, void* d_ws, size_t ws_size,
                              hipStream_t stream) {
    const float* x  = (const float*)d_in[0];
    const float* Wl = (const float*)d_in[1];
    const float* bl = (const float*)d_in[2];
    const float* Wn = (const float*)d_in[3];
    const float* bn = (const float*)d_in[4];
    float* out = (float*)d_out;

    int n_tokens = in_sizes[0] / N_EMBED;          // 16384
    int grid = (n_tokens + TM - 1) / TM;           // 512

    hipLaunchKernelGGL(noisy_topk_kernel, dim3(grid), dim3(256), 0, stream,
                       x, Wl, bl, Wn, bn, out, n_tokens);
}

// Round 6
// 276.508 us; speedup vs baseline: 28.0113x; 1.0060x over previous
//
#include <hip/hip_runtime.h>
#include <math.h>
#include <stdint.h>

#define N_EMBED   2048
#define N_EXPERTS 64
#define TOP_K     8
#define BLOCK     512
#define TM        32            // tokens per block
#define TW        4             // tokens per wave (8 waves/block)
#define KC        64            // K-chunk
#define NC        (N_EMBED / KC)

// monotone map fp64 -> u64 (bigger value => bigger key), low 6 bits = tie-break
// by lane so lower expert index wins ties (matches lax.top_k)
__device__ __forceinline__ uint64_t mono_key(double v, int lane) {
    uint64_t u = (uint64_t)__double_as_longlong(v);
    u = (u >> 63) ? ~u : (u | 0x8000000000000000ULL);
    return (u & ~63ULL) | (uint64_t)(63 - lane);
}
__device__ __forceinline__ double key_val(uint64_t k) {
    uint64_t u = k & ~63ULL;
    u = (u >> 63) ? (u & 0x7FFFFFFFFFFFFFFFULL) : ~u;
    return __longlong_as_double((long long)u);
}

__global__ __launch_bounds__(BLOCK, 4)
void noisy_topk_kernel(const float* __restrict__ x,
                       const float* __restrict__ Wl, const float* __restrict__ bl,
                       const float* __restrict__ Wn, const float* __restrict__ bn,
                       float* __restrict__ out, int n_tokens) {
    __shared__ double Wt[KC][N_EXPERTS];   // 32 KB, transposed: Wt[k][e]
    __shared__ double xs[TM][KC];          // 16 KB, fp64 x chunk

    const int tid  = threadIdx.x;
    const int lane = tid & 63;             // lane = expert
    const int wave = tid >> 6;             // 0..7
    const int t0   = blockIdx.x * TM;
    const int tb   = wave * TW;

    // fixed staging ownership (512 threads)
    const int se = tid >> 3;               // W: expert row 0..63
    const int sk = (tid & 7) * 8;          // W: 8 consecutive k
    const int st = tid >> 4;               // x: token 0..31
    const int sx = (tid & 15) * 4;         // x: 4 consecutive k

    double acc[TW];
#pragma unroll
    for (int t = 0; t < TW; ++t) acc[t] = 0.0;

    const double myb = (double)bl[lane] + (double)bn[lane];

    for (int c = 0; c < NC; ++c) {
        const int kc = c * KC;
        __syncthreads();                   // previous chunk's reads complete

        // ---- stage combined W chunk (fp64, transposed), coalesced reads ----
        const float* wlp = Wl + (size_t)se * N_EMBED + kc + sk;
        const float* wnp = Wn + (size_t)se * N_EMBED + kc + sk;
#pragma unroll
        for (int i = 0; i < 2; ++i) {
            const float4 a = *reinterpret_cast<const float4*>(wlp + 4 * i);
            const float4 b = *reinterpret_cast<const float4*>(wnp + 4 * i);
            Wt[sk + 4 * i + 0][se] = (double)a.x + (double)b.x;
            Wt[sk + 4 * i + 1][se] = (double)a.y + (double)b.y;
            Wt[sk + 4 * i + 2][se] = (double)a.z + (double)b.z;
            Wt[sk + 4 * i + 3][se] = (double)a.w + (double)b.w;
        }
        // ---- stage x chunk, converted to fp64 once here (not per-FMA) ----
        {
            const float* xp = x + (size_t)(t0 + st) * N_EMBED + kc + sx;
            const float4 a = *reinterpret_cast<const float4*>(xp);
            xs[st][sx + 0] = (double)a.x;
            xs[st][sx + 1] = (double)a.y;
            xs[st][sx + 2] = (double)a.z;
            xs[st][sx + 3] = (double)a.w;
        }
        __syncthreads();

        // ---- compute: lane = expert; W via b64, x via uniform broadcast ----
#pragma unroll 4
        for (int kk = 0; kk < KC; kk += 4) {
            const double w0 = Wt[kk + 0][lane];
            const double w1 = Wt[kk + 1][lane];
            const double w2 = Wt[kk + 2][lane];
            const double w3 = Wt[kk + 3][lane];
#pragma unroll
            for (int t = 0; t < TW; ++t) {
                const double2 p = *reinterpret_cast<const double2*>(&xs[tb + t][kk]);
                const double2 q = *reinterpret_cast<const double2*>(&xs[tb + t][kk + 2]);
                acc[t] = fma(p.x, w0, acc[t]);
                acc[t] = fma(p.y, w1, acc[t]);
                acc[t] = fma(q.x, w2, acc[t]);
                acc[t] = fma(q.y, w3, acc[t]);
            }
        }
    }

    // ---- wave-parallel top-8 + softmax + stores (verbatim from round 4) ----
    float* out_router = out;
    float* out_idx    = out + (size_t)n_tokens * N_EXPERTS;

#pragma unroll
    for (int t = 0; t < TW; ++t) {
        const double v = acc[t] + myb;
        uint64_t mykey = mono_key(v, lane);

        float pv[TOP_K]; int pi[TOP_K];
        double vtop0 = 0.0;
#pragma unroll
        for (int j = 0; j < TOP_K; ++j) {
            uint64_t k = mykey;
#pragma unroll
            for (int m = 32; m >= 1; m >>= 1) {
                uint64_t o = (uint64_t)__shfl_xor((unsigned long long)k, m);
                k = (o > k) ? o : k;
            }
            const int widx = 63 - (int)(k & 63);
            const double wv = key_val(k);
            if (j == 0) vtop0 = wv;
            pv[j] = __expf((float)(wv - vtop0));
            pi[j] = widx;
            if (lane == widx) mykey = 0;        // remove winner
        }
        float s = 0.f;
#pragma unroll
        for (int j = 0; j < TOP_K; ++j) s += pv[j];
        const float inv = 1.f / s;

        float r = 0.f;
#pragma unroll
        for (int j = 0; j < TOP_K; ++j) r = (lane == pi[j]) ? pv[j] * inv : r;
        out_router[(size_t)(t0 + tb + t) * N_EXPERTS + lane] = r;

        float iv = 0.f;
#pragma unroll
        for (int j = 0; j < TOP_K; ++j) iv = (lane == j) ? (float)pi[j] : iv;
        if (lane < TOP_K)
            out_idx[(size_t)(t0 + tb + t) * TOP_K + lane] = iv;
    }
}

extern "C" void kernel_launch(void* const* d_in, const int* in_sizes, int n_in,
                              void* d_out, int out_size, void* d_ws, size_t ws_size,
                              hipStream_t stream) {
    const float* x  = (const float*)d_in[0];
    const float* Wl = (const float*)d_in[1];
    const float* bl = (const float*)d_in[2];
    const float* Wn = (const float*)d_in[3];
    const float* bn = (const float*)d_in[4];
    float* out = (float*)d_out;

    int n_tokens = in_sizes[0] / N_EMBED;          // 16384
    int grid = (n_tokens + TM - 1) / TM;           // 512

    hipLaunchKernelGGL(noisy_topk_kernel, dim3(grid), dim3(BLOCK), 0, stream,
                       x, Wl, bl, Wn, bn, out, n_tokens);
}